// Round 4
// baseline (549.093 us; speedup 1.0000x reference)
//
#include <hip/hip_runtime.h>

#define THREADS 256
#define M_ROWS 32768
#define N_COLS 1024
#define K_DIM  4096
#define BM 128
#define BN 128
#define BK 64
#define NT (K_DIM / BK)

typedef __attribute__((ext_vector_type(8))) short bf16x8;
typedef __attribute__((ext_vector_type(4))) float f32x4;

// RNE float -> bf16 bits (finite inputs only)
static __device__ __forceinline__ unsigned int f2bf(float f) {
  unsigned int x = __builtin_bit_cast(unsigned int, f);
  return (x + 0x7fffu + ((x >> 16) & 1u)) >> 16;
}

// pack two f32 -> one dword of 2x bf16 (lo = a, hi = b), RNE
static __device__ __forceinline__ unsigned int cvt_pk_bf16(float a, float b) {
  unsigned int r;
  asm("v_cvt_pk_bf16_f32 %0, %1, %2" : "=v"(r) : "v"(a), "v"(b));
  return r;
}

// ---- prep: W2 fp32 -> bf16 ----
__global__ void prep_w2_kernel(const float* __restrict__ w2, unsigned short* __restrict__ w2b) {
  const size_t i = ((size_t)blockIdx.x * THREADS + threadIdx.x) * 8;
  const float4 a = *reinterpret_cast<const float4*>(w2 + i);
  const float4 b = *reinterpret_cast<const float4*>(w2 + i + 4);
  uint4 o;
  o.x = f2bf(a.x) | (f2bf(a.y) << 16);
  o.y = f2bf(a.z) | (f2bf(a.w) << 16);
  o.z = f2bf(b.x) | (f2bf(b.y) << 16);
  o.w = f2bf(b.z) | (f2bf(b.w) << 16);
  *reinterpret_cast<uint4*>(w2b + i) = o;
}

// ---- prep: W1cb[f][n] = bf16( W1[f][n] * cos(theta[n]) ), [4096][8] ----
__global__ void prep_w1_kernel(const float* __restrict__ w1, const float* __restrict__ theta,
                               unsigned short* __restrict__ w1cb) {
  const int i = blockIdx.x * THREADS + threadIdx.x;  // 32768
  w1cb[i] = (unsigned short)f2bf(w1[i] * cosf(theta[i & 7]));
}

// ---- prep: Qb[m][n] = bf16(cos(x[m][n])), n<8, [32768][8] ----
__global__ void prep_q_kernel(const float* __restrict__ x, unsigned short* __restrict__ qb) {
  const int i = blockIdx.x * THREADS + threadIdx.x;  // 262144
  qb[i] = (unsigned short)f2bf(cosf(x[((size_t)(i >> 3) << 10) + (i & 7)]));
}

// ---- fused GEMM: out[M][N] = relu(Q@W1c^T)[M][K] @ W2b^T ----
__global__ __launch_bounds__(THREADS) void fused_gemm(
    const unsigned short* __restrict__ W2b,   // [N][K] bf16 bits
    const unsigned short* __restrict__ W1cb,  // [K][8] bf16 bits
    const unsigned short* __restrict__ Qb,    // [M][8] bf16 bits
    float* __restrict__ out)                  // [M][N] fp32
{
  __shared__ __align__(16) char lds[(BM * BK + BN * BK) * 2];
  char* Alds = lds;                 // [128 m][64 f] bf16, byte ^= ((m&7)<<4)
  char* Blds = lds + BM * BK * 2;   // [128 n][64 f] bf16, byte ^= ((n&7)<<4)

  const int tid  = threadIdx.x;
  const int lane = tid & 63;
  const int wave = tid >> 6;
  const int bid  = blockIdx.x;
  const int gx = bid & 7;           // N-strip: same strip stays on one XCD (bid%8)
  const int gy = bid >> 3;          // M-tile
  const int row0 = gy * BM;
  const int col0 = gx * BN;
  const int l15 = lane & 15;

  // B staging source pre-swizzle: gload_lds writes lane*16 linearly; source
  // k-chunk = ((lane&7) ^ (row&7))*16 so that read-side XOR recovers true k.
  const int lhi = lane >> 3, llo = lane & 7;
  const int kb_src = (llo ^ lhi) << 4;

  const int wr = wave >> 1, wc = wave & 1;   // wave 64x64 sub-tile of C

  const bf16x8 zv = (bf16x8){0, 0, 0, 0, 0, 0, 0, 0};

  // Q fragments for H-MFMA (B-operand: col=m=lane&15, k=n; n>=8 -> 0).
  // Loop-invariant: wave covers m-frag rows {wave*32, wave*32+16}.
  bf16x8 qfrag[2];
#pragma unroll
  for (int mj = 0; mj < 2; ++mj) {
    qfrag[mj] = (lane < 16)
      ? *reinterpret_cast<const bf16x8*>(Qb + (size_t)(row0 + wave * 32 + mj * 16 + l15) * 8)
      : zv;
  }

  // W1c fragment prefetch: wcur used this tile, wnext issued early each tile.
  bf16x8 wcur[4], wnext[4];
#pragma unroll
  for (int fi = 0; fi < 4; ++fi) {
    wcur[fi] = (lane < 16)
      ? *reinterpret_cast<const bf16x8*>(W1cb + (size_t)(fi * 16 + l15) * 8)
      : zv;
  }

  f32x4 acc[4][4];
#pragma unroll
  for (int mi = 0; mi < 4; ++mi)
#pragma unroll
    for (int ni = 0; ni < 4; ++ni)
      acc[mi][ni] = (f32x4){0.f, 0.f, 0.f, 0.f};

  for (int kt = 0; kt < NT; ++kt) {
    const int f0 = kt * BK;

    // --- stage B tile: 4x global_load_lds per wave, linear dest, swizzled src ---
#pragma unroll
    for (int i = 0; i < 4; ++i) {
      const int nn = (wave * 4 + i) * 8 + lhi;
      const unsigned short* src =
          W2b + (size_t)(col0 + nn) * K_DIM + f0 + (kb_src >> 1);
      char* dst = Blds + (wave * 4 + i) * 1024;  // wave-uniform base; HW adds lane*16
      __builtin_amdgcn_global_load_lds(
          (const __attribute__((address_space(1))) void*)src,
          (__attribute__((address_space(3))) void*)dst, 16, 0, 0);
    }

    // --- prefetch next W1c fragments (latency hides under B staging) ---
    if (kt + 1 < NT) {
#pragma unroll
      for (int fi = 0; fi < 4; ++fi) {
        wnext[fi] = (lane < 16)
          ? *reinterpret_cast<const bf16x8*>(W1cb + (size_t)(f0 + BK + fi * 16 + l15) * 8)
          : zv;
      }
    }

    // --- stage A tile via H-MFMA: H = relu(W1c . Q), swapped operands ---
    // D frag: col=m=lane&15, row=f=(lane>>4)*4+r -> 4 consecutive f = 8B row chunk.
#pragma unroll
    for (int mj = 0; mj < 2; ++mj) {
      const int m = wave * 32 + mj * 16 + l15;   // tile-relative m-row
      char* rowp = Alds + m * 128;
      const int swz = (m & 7) << 4;
#pragma unroll
      for (int fi = 0; fi < 4; ++fi) {
        f32x4 hf = __builtin_amdgcn_mfma_f32_16x16x32_bf16(
            wcur[fi], qfrag[mj], (f32x4){0.f, 0.f, 0.f, 0.f}, 0, 0, 0);
        const unsigned int p0 = cvt_pk_bf16(fmaxf(hf[0], 0.f), fmaxf(hf[1], 0.f));
        const unsigned int p1 = cvt_pk_bf16(fmaxf(hf[2], 0.f), fmaxf(hf[3], 0.f));
        const int fb = fi * 32 + ((lane >> 4) << 3);  // byte offset in row (8B chunk)
        *reinterpret_cast<uint2*>(rowp + (fb ^ swz)) = uint2{p0, p1};
      }
    }

    __syncthreads();  // drains vmcnt (gload_lds + wnext) + lgkm (ds_write)

    // --- main MFMA: 2 k-steps of 32, 16 MFMA each per wave ---
#pragma unroll
    for (int ks = 0; ks < 2; ++ks) {
      const int kk = ks * 64 + ((lane >> 4) << 4);  // byte offset of lane's 8-bf16 chunk
      bf16x8 af[4], bfr[4];
#pragma unroll
      for (int mi = 0; mi < 4; ++mi) {
        const int rr = wr * 64 + mi * 16 + l15;
        af[mi] = *reinterpret_cast<const bf16x8*>(Alds + rr * 128 + (kk ^ ((rr & 7) << 4)));
      }
#pragma unroll
      for (int ni = 0; ni < 4; ++ni) {
        const int cc = wc * 64 + ni * 16 + l15;
        bfr[ni] = *reinterpret_cast<const bf16x8*>(Blds + cc * 128 + (kk ^ ((cc & 7) << 4)));
      }
#pragma unroll
      for (int mi = 0; mi < 4; ++mi)
#pragma unroll
        for (int ni = 0; ni < 4; ++ni)
          acc[mi][ni] = __builtin_amdgcn_mfma_f32_16x16x32_bf16(af[mi], bfr[ni], acc[mi][ni], 0, 0, 0);
    }

    __syncthreads();  // reads done before next stage overwrites

#pragma unroll
    for (int fi = 0; fi < 4; ++fi) wcur[fi] = wnext[fi];
  }

  // --- epilogue: C/D layout col=lane&15, row=(lane>>4)*4+reg ---
#pragma unroll
  for (int mi = 0; mi < 4; ++mi) {
#pragma unroll
    for (int ni = 0; ni < 4; ++ni) {
      const int cc = col0 + wc * 64 + ni * 16 + l15;
#pragma unroll
      for (int r = 0; r < 4; ++r) {
        const int rr = row0 + wr * 64 + mi * 16 + ((lane >> 4) << 2) + r;
        out[(size_t)rr * N_COLS + cc] = acc[mi][ni][r];
      }
    }
  }
}

extern "C" void kernel_launch(void* const* d_in, const int* in_sizes, int n_in,
                              void* d_out, int out_size, void* d_ws, size_t ws_size,
                              hipStream_t stream) {
  const float* x     = (const float*)d_in[0];
  const float* theta = (const float*)d_in[1];
  const float* W1    = (const float*)d_in[2];
  const float* W2    = (const float*)d_in[3];
  float* out = (float*)d_out;

  char* ws = (char*)d_ws;
  unsigned short* W2b  = (unsigned short*)ws;             // 8,388,608 B
  unsigned short* W1cb = (unsigned short*)(ws + 8388608); //    65,536 B
  unsigned short* Qb   = (unsigned short*)(ws + 8454144); //   524,288 B

  hipLaunchKernelGGL(prep_w2_kernel, dim3(2048), dim3(THREADS), 0, stream, W2, W2b);
  hipLaunchKernelGGL(prep_w1_kernel, dim3(128),  dim3(THREADS), 0, stream, W1, theta, W1cb);
  hipLaunchKernelGGL(prep_q_kernel,  dim3(1024), dim3(THREADS), 0, stream, x, Qb);
  hipLaunchKernelGGL(fused_gemm,     dim3(2048), dim3(THREADS), 0, stream, W2b, W1cb, Qb, out);
}

// Round 5
// 544.011 us; speedup vs baseline: 1.0093x; 1.0093x over previous
//
#include <hip/hip_runtime.h>

#define THREADS 512
#define M_ROWS 32768
#define N_COLS 1024
#define K_DIM  4096
#define BM 256
#define BN 256
#define BK 64
#define NT (K_DIM / BK)

typedef __attribute__((ext_vector_type(8))) short bf16x8;
typedef __attribute__((ext_vector_type(4))) float f32x4;

// RNE float -> bf16 bits (finite inputs only)
static __device__ __forceinline__ unsigned int f2bf(float f) {
  unsigned int x = __builtin_bit_cast(unsigned int, f);
  return (x + 0x7fffu + ((x >> 16) & 1u)) >> 16;
}

// pack two f32 -> one dword of 2x bf16 (lo = a, hi = b), RNE
static __device__ __forceinline__ unsigned int cvt_pk_bf16(float a, float b) {
  unsigned int r;
  asm("v_cvt_pk_bf16_f32 %0, %1, %2" : "=v"(r) : "v"(a), "v"(b));
  return r;
}

// ---- fused prep: W2->bf16 (blocks 0..2047), W1c (2048..2175), Q (2176..3199) ----
__global__ void prep_all(const float* __restrict__ x, const float* __restrict__ theta,
                         const float* __restrict__ w1, const float* __restrict__ w2,
                         unsigned short* __restrict__ w2b, unsigned short* __restrict__ w1cb,
                         unsigned short* __restrict__ qb) {
  const int b = blockIdx.x, tid = threadIdx.x;
  if (b < 2048) {
    const size_t i = ((size_t)b * 256 + tid) * 8;
    const float4 a = *reinterpret_cast<const float4*>(w2 + i);
    const float4 c = *reinterpret_cast<const float4*>(w2 + i + 4);
    uint4 o;
    o.x = f2bf(a.x) | (f2bf(a.y) << 16);
    o.y = f2bf(a.z) | (f2bf(a.w) << 16);
    o.z = f2bf(c.x) | (f2bf(c.y) << 16);
    o.w = f2bf(c.z) | (f2bf(c.w) << 16);
    *reinterpret_cast<uint4*>(w2b + i) = o;
  } else if (b < 2176) {
    const int i = (b - 2048) * 256 + tid;   // 32768
    w1cb[i] = (unsigned short)f2bf(w1[i] * cosf(theta[i & 7]));
  } else {
    const int i = (b - 2176) * 256 + tid;   // 262144
    qb[i] = (unsigned short)f2bf(cosf(x[((size_t)(i >> 3) << 10) + (i & 7)]));
  }
}

// ---- fused GEMM, 256x256 tile, 8 waves, 4-phase/K-tile schedule ----
__global__ __launch_bounds__(THREADS, 2) void fused_gemm(
    const unsigned short* __restrict__ W2b,   // [N][K] bf16 bits
    const unsigned short* __restrict__ W1cb,  // [K][8] bf16 bits
    const unsigned short* __restrict__ Qb,    // [M][8] bf16 bits
    float* __restrict__ out)                  // [M][N] fp32
{
  __shared__ __align__(16) char lds[131072];  // A dbuf 2x32KB + B dbuf 2x32KB
  char* const A0 = lds;
  char* const A1 = lds + 32768;
  char* const B0 = lds + 65536;
  char* const B1 = lds + 98304;

  const int tid  = threadIdx.x;
  const int lane = tid & 63;
  const int wave = tid >> 6;          // 0..7
  const int l15  = lane & 15;
  const int lhi = lane >> 3, llo = lane & 7;
  const int kb_src = (llo ^ lhi) << 4;       // source pre-swizzle for gload_lds
  const int wr = wave >> 2, wc = wave & 3;   // wave sub-tile: rows wr*128, cols wc*64

  // bijective XCD swizzle: 512 wgs = 8 xcds x 64; each XCD owns one gx half-strip
  const int o  = blockIdx.x;
  const int wg = (o & 7) * 64 + (o >> 3);
  const int gx = wg >> 7;              // 0..3
  const int gy = wg & 127;             // 0..127
  const int row0 = gy * BM;
  const int col0 = gx * BN;

  const bf16x8 zv = (bf16x8){0, 0, 0, 0, 0, 0, 0, 0};

  // Q fragments (H-MFMA B-operand): wave's 32 H-rows, loop-invariant
  bf16x8 qfrag[2];
#pragma unroll
  for (int mj = 0; mj < 2; ++mj)
    qfrag[mj] = (lane < 16)
      ? *reinterpret_cast<const bf16x8*>(Qb + (size_t)(row0 + wave * 32 + mj * 16 + l15) * 8)
      : zv;

  bf16x8 wcur[4], wnext[4];
#pragma unroll
  for (int fi = 0; fi < 4; ++fi)
    wcur[fi] = (lane < 16)
      ? *reinterpret_cast<const bf16x8*>(W1cb + (size_t)(fi * 16 + l15) * 8)
      : zv;

  // ---- prologue: generate A[0] (f=0..64), stage B[0], reload wcur for f=64 ----
#pragma unroll
  for (int mj = 0; mj < 2; ++mj) {
    const int m = wave * 32 + mj * 16 + l15;
    char* rowp = A0 + m * 128;
    const int swz = (m & 7) << 4;
#pragma unroll
    for (int fi = 0; fi < 4; ++fi) {
      f32x4 hf = __builtin_amdgcn_mfma_f32_16x16x32_bf16(
          wcur[fi], qfrag[mj], (f32x4){0.f, 0.f, 0.f, 0.f}, 0, 0, 0);
      const unsigned int p0 = cvt_pk_bf16(fmaxf(hf[0], 0.f), fmaxf(hf[1], 0.f));
      const unsigned int p1 = cvt_pk_bf16(fmaxf(hf[2], 0.f), fmaxf(hf[3], 0.f));
      const int fb = fi * 32 + ((lane >> 4) << 3);
      *reinterpret_cast<uint2*>(rowp + (fb ^ swz)) = uint2{p0, p1};
    }
  }
#pragma unroll
  for (int i = 0; i < 4; ++i) {
    const int nn = i * 64 + wave * 8 + lhi;
    const unsigned short* src = W2b + (size_t)(col0 + nn) * K_DIM + (kb_src >> 1);
    char* dst = B0 + (i * 64 + wave * 8) * 128;
    __builtin_amdgcn_global_load_lds(
        (const __attribute__((address_space(1))) void*)src,
        (__attribute__((address_space(3))) void*)dst, 16, 0, 0);
  }
#pragma unroll
  for (int fi = 0; fi < 4; ++fi)
    wcur[fi] = (lane < 16)
      ? *reinterpret_cast<const bf16x8*>(W1cb + (size_t)(BK + fi * 16 + l15) * 8)
      : zv;
  __syncthreads();

  f32x4 acc[8][4];
#pragma unroll
  for (int mi = 0; mi < 8; ++mi)
#pragma unroll
    for (int ni = 0; ni < 4; ++ni)
      acc[mi][ni] = (f32x4){0.f, 0.f, 0.f, 0.f};

  char *Acur = A0, *Anxt = A1, *Bcur = B0, *Bnxt = B1;

  for (int kt = 0; kt < NT; ++kt) {
    const bool gen = (kt + 1 < NT);
    const int f1 = (kt + 1) * BK;
    bf16x8 bfr[4][2];   // all 4 n-frags x 2 ks, resident across the tile
    bf16x8 af[2][2];    // this phase's 2 m-frags x 2 ks

#pragma unroll
    for (int P = 0; P < 4; ++P) {
      // --- A-frag ds_reads for this phase's m-pair {2P, 2P+1} ---
#pragma unroll
      for (int m2 = 0; m2 < 2; ++m2) {
        const int rr = wr * 128 + (2 * P + m2) * 16 + l15;
        const int rbase = rr * 128;
        const int rswz = (rr & 7) << 4;
#pragma unroll
        for (int ks = 0; ks < 2; ++ks) {
          const int kk = ks * 64 + ((lane >> 4) << 4);
          af[m2][ks] = *reinterpret_cast<const bf16x8*>(Acur + rbase + (kk ^ rswz));
        }
      }
      if (P == 0) {
        // --- all B-frags (8 reads), resident for the tile ---
#pragma unroll
        for (int ni = 0; ni < 4; ++ni) {
          const int cc = wc * 64 + ni * 16 + l15;
          const int cbase = cc * 128;
          const int cswz = (cc & 7) << 4;
#pragma unroll
          for (int ks = 0; ks < 2; ++ks) {
            const int kk = ks * 64 + ((lane >> 4) << 4);
            bfr[ni][ks] = *reinterpret_cast<const bf16x8*>(Bcur + cbase + (kk ^ cswz));
          }
        }
        if (gen) {
          // --- issue B[kt+1] gloads (awaited at tile-end sync, ~3 phases later) ---
#pragma unroll
          for (int i = 0; i < 4; ++i) {
            const int nn = i * 64 + wave * 8 + lhi;
            const unsigned short* src = W2b + (size_t)(col0 + nn) * K_DIM + f1 + (kb_src >> 1);
            char* dst = Bnxt + (i * 64 + wave * 8) * 128;
            __builtin_amdgcn_global_load_lds(
                (const __attribute__((address_space(1))) void*)src,
                (__attribute__((address_space(3))) void*)dst, 16, 0, 0);
          }
          const int fw = (kt + 2 < NT ? kt + 2 : NT - 1) * BK;
#pragma unroll
          for (int fi = 0; fi < 4; ++fi)
            wnext[fi] = (lane < 16)
              ? *reinterpret_cast<const bf16x8*>(W1cb + (size_t)(fw + fi * 16 + l15) * 8)
              : zv;
        }
      }
      if (gen) {
        // --- H-gen slice: mj=P>>1, fi in {(P&1)*2, +1} -> A[kt+1] ---
        const int mj = P >> 1;
        const int m = wave * 32 + mj * 16 + l15;
        char* rowp = Anxt + m * 128;
        const int swz = (m & 7) << 4;
#pragma unroll
        for (int t = 0; t < 2; ++t) {
          const int fi = (P & 1) * 2 + t;
          f32x4 hf = __builtin_amdgcn_mfma_f32_16x16x32_bf16(
              wcur[fi], qfrag[mj], (f32x4){0.f, 0.f, 0.f, 0.f}, 0, 0, 0);
          const unsigned int p0 = cvt_pk_bf16(fmaxf(hf[0], 0.f), fmaxf(hf[1], 0.f));
          const unsigned int p1 = cvt_pk_bf16(fmaxf(hf[2], 0.f), fmaxf(hf[3], 0.f));
          const int fb = fi * 32 + ((lane >> 4) << 3);
          *reinterpret_cast<uint2*>(rowp + (fb ^ swz)) = uint2{p0, p1};
        }
      }
      __builtin_amdgcn_s_barrier();
      asm volatile("s_waitcnt lgkmcnt(0)" ::: "memory");
      __builtin_amdgcn_sched_barrier(0);   // rule 18: keep MFMA below the wait
      __builtin_amdgcn_s_setprio(1);
#pragma unroll
      for (int ks = 0; ks < 2; ++ks)
#pragma unroll
        for (int m2 = 0; m2 < 2; ++m2)
#pragma unroll
          for (int ni = 0; ni < 4; ++ni)
            acc[2 * P + m2][ni] = __builtin_amdgcn_mfma_f32_16x16x32_bf16(
                af[m2][ks], bfr[ni][ks], acc[2 * P + m2][ni], 0, 0, 0);
      __builtin_amdgcn_s_setprio(0);
      if (P < 3) __builtin_amdgcn_s_barrier();
      else       __syncthreads();   // tile-end: drains gloads (vmcnt) + H-writes (lgkm)
    }
    { char* t = Acur; Acur = Anxt; Anxt = t; t = Bcur; Bcur = Bnxt; Bnxt = t; }
#pragma unroll
    for (int fi = 0; fi < 4; ++fi) wcur[fi] = wnext[fi];
  }

  // --- epilogue: C/D layout col=lane&15, row=(lane>>4)*4+reg ---
#pragma unroll
  for (int mi = 0; mi < 8; ++mi) {
#pragma unroll
    for (int ni = 0; ni < 4; ++ni) {
      const int cc = col0 + wc * 64 + ni * 16 + l15;
#pragma unroll
      for (int r = 0; r < 4; ++r) {
        const int rr = row0 + wr * 128 + mi * 16 + ((lane >> 4) << 2) + r;
        out[(size_t)rr * N_COLS + cc] = acc[mi][ni][r];
      }
    }
  }
}

extern "C" void kernel_launch(void* const* d_in, const int* in_sizes, int n_in,
                              void* d_out, int out_size, void* d_ws, size_t ws_size,
                              hipStream_t stream) {
  const float* x     = (const float*)d_in[0];
  const float* theta = (const float*)d_in[1];
  const float* W1    = (const float*)d_in[2];
  const float* W2    = (const float*)d_in[3];
  float* out = (float*)d_out;

  char* ws = (char*)d_ws;
  unsigned short* W2b  = (unsigned short*)ws;             // 8,388,608 B
  unsigned short* W1cb = (unsigned short*)(ws + 8388608); //    65,536 B
  unsigned short* Qb   = (unsigned short*)(ws + 8454144); //   524,288 B

  hipLaunchKernelGGL(prep_all, dim3(3200), dim3(256), 0, stream,
                     x, theta, W1, W2, W2b, W1cb, Qb);
  hipLaunchKernelGGL(fused_gemm, dim3(512), dim3(THREADS), 0, stream,
                     W2b, W1cb, Qb, out);
}